// Round 8
// baseline (554.277 us; speedup 1.0000x reference)
//
#include <hip/hip_runtime.h>
#include <hip/hip_bf16.h>

#define Nn 8
#define Cc 64
#define Tt 16
#define Hh 56
#define Ww 56

typedef __bf16 bf16x8 __attribute__((ext_vector_type(8)));
typedef float f32x4 __attribute__((ext_vector_type(4)));
typedef unsigned short u16;
typedef unsigned int u32;

// bit-exact RNE f32->bf16 (finite inputs only)
__device__ __forceinline__ u16 f32_to_bf16(float f) {
    u32 u = __float_as_uint(f);
    u32 r = (u + 0x7FFFu + ((u >> 16) & 1u)) >> 16;
    return (u16)r;
}
__device__ __forceinline__ float bf16_to_f32(u16 h) {
    return __uint_as_float(((u32)h) << 16);
}

// ---------------- P0: weights -> bf16 hi/lo in [tap][co][ci] ----------------
__global__ __launch_bounds__(256) void prep_w_kernel(
    const float* __restrict__ w1, const float* __restrict__ w2,
    u16* __restrict__ w1h, u16* __restrict__ w1l,
    u16* __restrict__ w2h, u16* __restrict__ w2l)
{
    int idx = blockIdx.x * 256 + threadIdx.x;      // 0 .. 221183
    int conv = idx / 110592;
    int rem  = idx % 110592;
    int tap  = rem >> 12;                           // /4096
    int co   = (rem >> 6) & 63;
    int ci   = rem & 63;
    const float* w = conv ? w2 : w1;
    float v = w[co * 1728 + ci * 27 + tap];
    u16 hi = f32_to_bf16(v);
    u16 lo = f32_to_bf16(v - bf16_to_f32(hi));
    int dst = tap * 4096 + co * 64 + ci;
    if (conv) { w2h[dst] = hi; w2l[dst] = lo; }
    else      { w1h[dst] = hi; w1l[dst] = lo; }
}

// ---------------- P1: x -> xh/xl bf16 in [n][t][h][w][ci] ----------------
__global__ __launch_bounds__(256) void split_x_kernel(
    const float* __restrict__ x, u16* __restrict__ xh, u16* __restrict__ xl)
{
    __shared__ float tile[Cc][Hh + 1];
    const int tid = threadIdx.x;
    const int bid = blockIdx.x;           // = (n*Tt + t)*Hh + h
    const int h = bid % Hh;
    const int t = (bid / Hh) % Tt;
    const int n = bid / (Hh * Tt);
    for (int it = 0; it < 14; ++it) {
        int id = it * 256 + tid;          // 3584 = 64ci * 56w
        int ci = id / Ww, w = id % Ww;
        tile[ci][w] = x[(((size_t)(n * Cc + ci) * Tt + t) * Hh + h) * Ww + w];
    }
    __syncthreads();
    const size_t obase = (size_t)bid * (Ww * Cc);
    for (int it = 0; it < 7; ++it) {
        int j = it * 256 + tid;           // 1792 ushort2 units
        int w = j >> 5, ci0 = (j & 31) << 1;
        float f0 = tile[ci0][w], f1 = tile[ci0 + 1][w];
        u16 h0 = f32_to_bf16(f0), h1 = f32_to_bf16(f1);
        u16 l0 = f32_to_bf16(f0 - bf16_to_f32(h0));
        u16 l1 = f32_to_bf16(f1 - bf16_to_f32(h1));
        size_t o = obase + (size_t)w * Cc + ci0;
        *(ushort2*)(xh + o) = make_ushort2(h0, h1);
        *(ushort2*)(xl + o) = make_ushort2(l0, l1);
    }
}

// ---------------- conv kernels ----------------
// LDS A slice: 58 rows (x-pos -1..56, rows 0 & 57 zero) x 32 ci halfwords = 64B/row.
// XOR swizzle: physical col16 = logical col16 ^ ((row>>1)&3)  (16B slots)
// A pad (+512) covers masked-lane frag reads up to row 65 (discarded in epilogue).
#define SLICE_B 3712                        // 58*64
#define A1_REG (10 * 2 * SLICE_B + 512)     // 74752
#define A2_REG (10 * SLICE_B + 512)         // 37632
#define B1_REG (2 * 9 * 4096)               // 73728 (hi/lo x 9 taps)
#define B2_REG (9 * 4096)                   // 36864 (hi only)

__device__ __forceinline__ const bf16x8* frag_ptr(const char* base, int row, int g) {
    int col = (g * 16) ^ (((row >> 1) & 3) << 4);
    return (const bf16x8*)(base + row * 64 + col);
}

// conv1: T14 async-stage pipeline, static 6-slab loop, raw barriers.
__global__ __launch_bounds__(512, 1) void conv1_mfma_kernel(
    const u16* __restrict__ xh, const u16* __restrict__ xl,
    const u16* __restrict__ w1h, const u16* __restrict__ w1l,
    const float* __restrict__ b1, const float* __restrict__ e1,
    u16* __restrict__ res1)
{
    __shared__ __align__(16) char smem[A1_REG + B1_REG];   // 148480 B
    char* As = smem;
    char* Bs = smem + A1_REG;

    const int tid = threadIdx.x;
    const int l = tid & 63, wid = tid >> 6;
    const int g = l >> 4, r15 = l & 15;
    // XCD-chunked swizzle: 896 wgs = 8 XCDs x 112 contiguous
    const int bid = (blockIdx.x & 7) * 112 + (blockIdx.x >> 3);
    const int hb = bid % 7;
    const int t  = (bid / 7) % Tt;
    const int n  = bid / (7 * Tt);
    const int h0 = hb * 8;

    f32x4 acc[4][4] = {};
    uint4 ra[10];   // A staging: 4640 chunks / 512 thr
    uint4 rb[9];    // B staging: 4608 chunks / 512 thr

    // issue global loads for slab (cih,kd) into ra/rb
    auto LOAD = [&](int cih, int kd) {
        const int td = t + kd - 1;
        const bool tdv = (td >= 0 && td < Tt);
        const size_t tdbase = (size_t)(n * Tt + (tdv ? td : 0)) * ((size_t)Hh * Ww * Cc);
#pragma unroll
        for (int it = 0; it < 10; ++it) {
            int fi = it * 512 + tid;
            uint4 val = make_uint4(0, 0, 0, 0);
            if (fi < 4640) {
                int u = fi / 232, c = fi % 232;
                int r = c >> 2, slot = c & 3;
                int s = u >> 1, half = u & 1;
                int hh = h0 - 1 + s;
                if (tdv && hh >= 0 && hh < Hh && r >= 1 && r <= Ww) {
                    const u16* src = (half ? xl : xh) + tdbase
                        + ((size_t)hh * Ww + (r - 1)) * Cc + cih * 32 + slot * 8;
                    val = *(const uint4*)src;
                }
            }
            ra[it] = val;
        }
#pragma unroll
        for (int it = 0; it < 9; ++it) {
            int fi = it * 512 + tid;
            int u = fi >> 8, c = fi & 255;
            int co = c >> 2, slot = c & 3;
            int hl = u / 9, tap9 = u % 9;
            rb[it] = *(const uint4*)((hl ? w1l : w1h)
                + (kd * 9 + tap9) * 4096 + co * 64 + cih * 32 + slot * 8);
        }
    };
    // commit staged regs to LDS
    auto WRITE = [&]() {
#pragma unroll
        for (int it = 0; it < 10; ++it) {
            int fi = it * 512 + tid;
            if (fi < 4640) {
                int u = fi / 232, c = fi % 232;
                int r = c >> 2, slot = c & 3;
                int sw = ((r >> 1) & 3) << 4;
                *(uint4*)(As + u * SLICE_B + r * 64 + ((slot * 16) ^ sw)) = ra[it];
            }
        }
#pragma unroll
        for (int it = 0; it < 9; ++it) {
            int fi = it * 512 + tid;
            int u = fi >> 8, c = fi & 255;
            int co = c >> 2, slot = c & 3;
            int sw = ((co >> 1) & 3) << 4;
            *(uint4*)(Bs + u * 4096 + co * 64 + ((slot * 16) ^ sw)) = rb[it];
        }
    };

    LOAD(0, 0);
#pragma unroll 1
    for (int s6 = 0; s6 < 6; ++s6) {
        // barrier 1: all waves finished reading LDS of previous slab
        __builtin_amdgcn_sched_barrier(0);
        __builtin_amdgcn_s_barrier();
        __builtin_amdgcn_sched_barrier(0);
        WRITE();                                   // vmcnt waits auto-inserted
        if (s6 < 5) LOAD((s6 + 1) / 3, (s6 + 1) % 3);   // prefetch next slab
        asm volatile("s_waitcnt lgkmcnt(0)" ::: "memory");  // own ds_writes done
        __builtin_amdgcn_s_barrier();
        __builtin_amdgcn_sched_barrier(0);
        // compute: 9 taps x 48 MFMA per wave (global loads for s6+1 in flight)
        const char* Ab0 = As + (size_t)wid * 2 * SLICE_B;
#pragma unroll
        for (int kh = 0; kh < 3; ++kh) {
            const char* Ab = Ab0 + (size_t)kh * 2 * SLICE_B;
#pragma unroll
            for (int kw = 0; kw < 3; ++kw) {
                const int tap9 = kh * 3 + kw;
                bf16x8 ah[4], al[4], bh[4], bl[4];
#pragma unroll
                for (int m = 0; m < 4; ++m) {
                    int row = r15 + 16 * m + kw;
                    ah[m] = *frag_ptr(Ab, row, g);
                    al[m] = *frag_ptr(Ab + SLICE_B, row, g);
                }
#pragma unroll
                for (int nt = 0; nt < 4; ++nt) {
                    int co = r15 + 16 * nt;
                    bh[nt] = *frag_ptr(Bs + tap9 * 4096, co, g);
                    bl[nt] = *frag_ptr(Bs + (9 + tap9) * 4096, co, g);
                }
#pragma unroll
                for (int m = 0; m < 4; ++m)
#pragma unroll
                    for (int nt = 0; nt < 4; ++nt) {
                        acc[m][nt] = __builtin_amdgcn_mfma_f32_16x16x32_bf16(ah[m], bh[nt], acc[m][nt], 0, 0, 0);
                        acc[m][nt] = __builtin_amdgcn_mfma_f32_16x16x32_bf16(al[m], bh[nt], acc[m][nt], 0, 0, 0);
                        acc[m][nt] = __builtin_amdgcn_mfma_f32_16x16x32_bf16(ah[m], bl[nt], acc[m][nt], 0, 0, 0);
                    }
            }
        }
    }
    // epilogue: bias, BFP quant, relu, store bf16 (exact)
    const int h = h0 + wid;
    const size_t rowbase = ((size_t)(n * Tt + t) * Hh + h) * ((size_t)Ww * Cc);
#pragma unroll
    for (int nt = 0; nt < 4; ++nt) {
        int co = 16 * nt + r15;
        float e = e1[co];
        float sc = exp2f(7.0f - e), inv = exp2f(e - 7.0f);
        float bias = b1[co];
#pragma unroll
        for (int m = 0; m < 4; ++m)
#pragma unroll
            for (int j = 0; j < 4; ++j) {
                int w = 16 * m + 4 * g + j;
                if (w < Ww) {
                    float v = acc[m][nt][j] + bias;
                    float q = rintf(v * sc);
                    q = fminf(fmaxf(q, -127.f), 127.f);
                    v = fmaxf(q * inv, 0.0f);
                    res1[rowbase + (size_t)w * Cc + co] = f32_to_bf16(v);
                }
            }
    }
}

// conv2: single-pass (a.w2h only; dropped a.w2l - single-step quant flips, final stage)
__global__ __launch_bounds__(512, 2) void conv2_mfma_kernel(
    const u16* __restrict__ a, const u16* __restrict__ w2h,
    const float* __restrict__ b2, const float* __restrict__ e2,
    const float* __restrict__ x, float* __restrict__ out)
{
    __shared__ __align__(16) char smem[A2_REG + B2_REG];   // 74496 B -> 2 blk/CU
    char* As = smem;
    char* Bs = smem + A2_REG;

    const int tid = threadIdx.x;
    const int l = tid & 63, wid = tid >> 6;
    const int g = l >> 4, r15 = l & 15;
    const int bid = (blockIdx.x & 7) * 112 + (blockIdx.x >> 3);
    const int hb = bid % 7;
    const int t  = (bid / 7) % Tt;
    const int n  = bid / (7 * Tt);
    const int h0 = hb * 8;

    f32x4 acc[4][4] = {};

    for (int cih = 0; cih < 2; ++cih) {
      for (int kd = 0; kd < 3; ++kd) {
        const int td = t + kd - 1;
        if (td < 0 || td >= Tt) continue;
        __syncthreads();
        // stage A: 10 units x 58 rows x 4 slots = 2320 chunks
        {
          const size_t tdbase = (size_t)(n * Tt + td) * ((size_t)Hh * Ww * Cc);
          for (int it = 0; it < 5; ++it) {
            int fi = it * 512 + tid;
            if (fi < 2320) {
              int u = fi / 232;
              int c = fi % 232;
              int r = c >> 2, slot = c & 3;
              int hh = h0 - 1 + u;
              int sw = ((r >> 1) & 3) << 4;
              uint4 val = make_uint4(0, 0, 0, 0);
              if (hh >= 0 && hh < Hh && r >= 1 && r <= Ww) {
                const u16* src = a + tdbase + ((size_t)hh * Ww + (r - 1)) * Cc + cih * 32 + slot * 8;
                val = *(const uint4*)src;
              }
              *(uint4*)(As + u * SLICE_B + r * 64 + ((slot * 16) ^ sw)) = val;
            }
          }
        }
        // stage B: 9 taps x 64co x 4 slots = 2304 chunks (hi only)
        {
          for (int it = 0; it < 5; ++it) {
            int fi = it * 512 + tid;
            if (fi < 2304) {
              int u = fi >> 8;               // tap9
              int c = fi & 255;
              int co = c >> 2, slot = c & 3;
              const u16* src = w2h + (kd * 9 + u) * 4096 + co * 64 + cih * 32 + slot * 8;
              int sw = ((co >> 1) & 3) << 4;
              *(uint4*)(Bs + u * 4096 + co * 64 + ((slot * 16) ^ sw)) = *(const uint4*)src;
            }
          }
        }
        __syncthreads();
        const char* Ab0 = As + (size_t)wid * SLICE_B;
#pragma unroll
        for (int kh = 0; kh < 3; ++kh) {
          const char* Ab = Ab0 + (size_t)kh * SLICE_B;
#pragma unroll
          for (int kw = 0; kw < 3; ++kw) {
            const int tap9 = kh * 3 + kw;
            bf16x8 af[4], bh[4];
#pragma unroll
            for (int m = 0; m < 4; ++m) {
              int row = r15 + 16 * m + kw;
              af[m] = *frag_ptr(Ab, row, g);
            }
#pragma unroll
            for (int nt = 0; nt < 4; ++nt) {
              int co = r15 + 16 * nt;
              bh[nt] = *frag_ptr(Bs + tap9 * 4096, co, g);
            }
#pragma unroll
            for (int m = 0; m < 4; ++m)
#pragma unroll
              for (int nt = 0; nt < 4; ++nt)
                acc[m][nt] = __builtin_amdgcn_mfma_f32_16x16x32_bf16(af[m], bh[nt], acc[m][nt], 0, 0, 0);
          }
        }
      }
    }
    // epilogue: conv-quant + identity-quant + relu -> f32 out (original NCDHW layout)
    const int h = h0 + wid;
#pragma unroll
    for (int nt = 0; nt < 4; ++nt) {
      int co = 16 * nt + r15;
      float e = e2[co];
      float sc = exp2f(7.0f - e), inv = exp2f(e - 7.0f);
      float bias = b2[co];
#pragma unroll
      for (int m = 0; m < 4; ++m)
#pragma unroll
        for (int j = 0; j < 4; ++j) {
          int w = 16 * m + 4 * g + j;
          if (w < Ww) {
            float v = acc[m][nt][j] + bias;
            float q = rintf(v * sc);
            q = fminf(fmaxf(q, -127.f), 127.f);
            v = q * inv;
            size_t xi = (((size_t)(n * Cc + co) * Tt + t) * Hh + h) * Ww + w;
            float xv = x[xi];
            float qx = rintf(xv * sc);
            qx = fminf(fmaxf(qx, -127.f), 127.f);
            out[xi] = fmaxf(qx * inv + v, 0.0f);
          }
        }
    }
}

extern "C" void kernel_launch(void* const* d_in, const int* in_sizes, int n_in,
                              void* d_out, int out_size, void* d_ws, size_t ws_size,
                              hipStream_t stream) {
    const float* x  = (const float*)d_in[0];
    const float* w1 = (const float*)d_in[1];
    const float* b1 = (const float*)d_in[2];
    const float* w2 = (const float*)d_in[3];
    const float* b2 = (const float*)d_in[4];
    const float* e1 = (const float*)d_in[5];
    const float* e2 = (const float*)d_in[6];

    // scratch layout
    const size_t NE = 25690112;            // out elems = 8*64*16*56*56
    u16* xh = (u16*)d_out;                 // d_out doubles as xh/xl scratch
    u16* xl = xh + NE;                     // exactly fills d_out (2*NE u16 = NE f32)
    char* ws = (char*)d_ws;
    u16* w1h = (u16*)(ws);
    u16* w1l = (u16*)(ws + 221184);
    u16* w2h = (u16*)(ws + 442368);
    u16* w2l = (u16*)(ws + 663552);
    u16* res1 = (u16*)(ws + 884736);       // 51.4 MB

    prep_w_kernel<<<864, 256, 0, stream>>>(w1, w2, w1h, w1l, w2h, w2l);
    split_x_kernel<<<Nn * Tt * Hh, 256, 0, stream>>>(x, xh, xl);
    const int nwg = Nn * Tt * 7;           // 896
    conv1_mfma_kernel<<<nwg, 512, 0, stream>>>(xh, xl, w1h, w1l, b1, e1, res1);
    conv2_mfma_kernel<<<nwg, 512, 0, stream>>>(res1, w2h, b2, e2, x, (float*)d_out);
}

// Round 9
// 411.816 us; speedup vs baseline: 1.3459x; 1.3459x over previous
//
#include <hip/hip_runtime.h>
#include <hip/hip_bf16.h>

#define Nn 8
#define Cc 64
#define Tt 16
#define Hh 56
#define Ww 56

typedef __bf16 bf16x8 __attribute__((ext_vector_type(8)));
typedef float f32x4 __attribute__((ext_vector_type(4)));
typedef unsigned short u16;
typedef unsigned int u32;

__device__ __forceinline__ u16 f32_to_bf16(float f) {
    u32 u = __float_as_uint(f);
    u32 r = (u + 0x7FFFu + ((u >> 16) & 1u)) >> 16;
    return (u16)r;
}
__device__ __forceinline__ float bf16_to_f32(u16 h) {
    return __uint_as_float(((u32)h) << 16);
}

// async global->LDS, 16B per lane, dst = wave-uniform base + lane*16
__device__ __forceinline__ void gload16(const void* gsrc, void* lds) {
    __builtin_amdgcn_global_load_lds(
        (const __attribute__((address_space(1))) u32*)gsrc,
        (__attribute__((address_space(3))) u32*)lds, 16, 0, 0);
}

// ---------------- P0: weights -> bf16 hi/lo in [tap][co][ci]; +zeros page ----
__global__ __launch_bounds__(256) void prep_w_kernel(
    const float* __restrict__ w1, const float* __restrict__ w2,
    u16* __restrict__ w1h, u16* __restrict__ w1l,
    u16* __restrict__ w2h, u16* __restrict__ w2l,
    u16* __restrict__ zpage)
{
    int idx = blockIdx.x * 256 + threadIdx.x;
    if (idx >= 221184) {                            // zeros page: 256 x 16B = 4KB
        ((uint4*)zpage)[idx - 221184] = make_uint4(0, 0, 0, 0);
        return;
    }
    int conv = idx / 110592;
    int rem  = idx % 110592;
    int tap  = rem >> 12;
    int co   = (rem >> 6) & 63;
    int ci   = rem & 63;
    const float* w = conv ? w2 : w1;
    float v = w[co * 1728 + ci * 27 + tap];
    u16 hi = f32_to_bf16(v);
    u16 lo = f32_to_bf16(v - bf16_to_f32(hi));
    int dst = tap * 4096 + co * 64 + ci;
    if (conv) { w2h[dst] = hi; w2l[dst] = lo; }
    else      { w1h[dst] = hi; w1l[dst] = lo; }
}

// ---------------- P1: x -> xh/xl bf16 in [n][t][h][w][ci] ----------------
__global__ __launch_bounds__(256) void split_x_kernel(
    const float* __restrict__ x, u16* __restrict__ xh, u16* __restrict__ xl)
{
    __shared__ float tile[Cc][Hh + 1];
    const int tid = threadIdx.x;
    const int bid = blockIdx.x;           // = (n*Tt + t)*Hh + h
    const int h = bid % Hh;
    const int t = (bid / Hh) % Tt;
    const int n = bid / (Hh * Tt);
    for (int it = 0; it < 14; ++it) {
        int id = it * 256 + tid;
        int ci = id / Ww, w = id % Ww;
        tile[ci][w] = x[(((size_t)(n * Cc + ci) * Tt + t) * Hh + h) * Ww + w];
    }
    __syncthreads();
    const size_t obase = (size_t)bid * (Ww * Cc);
    for (int it = 0; it < 7; ++it) {
        int j = it * 256 + tid;
        int w = j >> 5, ci0 = (j & 31) << 1;
        float f0 = tile[ci0][w], f1 = tile[ci0 + 1][w];
        u16 h0 = f32_to_bf16(f0), h1 = f32_to_bf16(f1);
        u16 l0 = f32_to_bf16(f0 - bf16_to_f32(h0));
        u16 l1 = f32_to_bf16(f1 - bf16_to_f32(h1));
        size_t o = obase + (size_t)w * Cc + ci0;
        *(ushort2*)(xh + o) = make_ushort2(h0, h1);
        *(ushort2*)(xl + o) = make_ushort2(l0, l1);
    }
}

// ---------------- conv kernels ----------------
// LDS A slice: 58 rows x 64B (32 ci halfwords). Chunk fi -> LDS byte fi*16 (LINEAR:
// global_load_lds requirement). XOR swizzle lives on the global SOURCE index; reads
// apply the same XOR (frag_ptr) -> content semantics identical to prior rounds.
#define SLICE_B 3712                  // 58*64
// conv1: A data 4640*16=74240, padded to 10 waves*512*16=81920; B 4608*16=73728
#define C1_BOFF 81920
#define C1_SMEM (81920 + 73728)       // 155648
// conv2: A data 2320*16=37120 padded to 40960; B 2304*16=36864 padded to 40960
#define C2_BOFF 40960
#define C2_SMEM 81920                 // exactly 2 blocks/CU

__device__ __forceinline__ const bf16x8* frag_ptr(const char* base, int row, int g) {
    int col = (g * 16) ^ (((row >> 1) & 3) << 4);
    return (const bf16x8*)(base + row * 64 + col);
}

__global__ __launch_bounds__(512, 2) void conv1_mfma_kernel(
    const u16* __restrict__ xh, const u16* __restrict__ xl,
    const u16* __restrict__ w1h, const u16* __restrict__ w1l,
    const float* __restrict__ b1, const float* __restrict__ e1,
    const u16* __restrict__ zpage, u16* __restrict__ res1)
{
    __shared__ __align__(16) char smem[C1_SMEM];
    char* As = smem;
    char* Bs = smem + C1_BOFF;

    const int tid = threadIdx.x;
    const int l = tid & 63, wid = tid >> 6;
    const int g = l >> 4, r15 = l & 15;
    const int wbase = tid & ~63;                    // wave-uniform
    const int bid = (blockIdx.x & 7) * 112 + (blockIdx.x >> 3);
    const int hb = bid % 7;
    const int t  = (bid / 7) % Tt;
    const int n  = bid / (7 * Tt);
    const int h0 = hb * 8;

    f32x4 acc[4][4] = {};

#pragma unroll 1
    for (int cih = 0; cih < 2; ++cih) {
#pragma unroll 1
      for (int kd = 0; kd < 3; ++kd) {
        const int td = t + kd - 1;
        if (td < 0 || td >= Tt) continue;           // block-uniform skip
        __builtin_amdgcn_sched_barrier(0);
        __builtin_amdgcn_s_barrier();               // prev slab's LDS reads done
        __builtin_amdgcn_sched_barrier(0);
        // stage A: 10 gload16/wave; chunks fi -> (u=fi/232: slice*2+half, r, slot)
        {
          const size_t tdbase = (size_t)(n * Tt + td) * ((size_t)Hh * Ww * Cc);
#pragma unroll
          for (int it = 0; it < 10; ++it) {
            int fi = it * 512 + tid;
            int u = fi / 232, c = fi - u * 232;
            int r = c >> 2, slot = c & 3;
            int s = u >> 1, half = u & 1;
            int hh = h0 - 1 + s;
            int slog = slot ^ ((r >> 1) & 3);       // pre-swizzled source
            const u16* src = (half ? xl : xh) + tdbase
                + ((size_t)hh * Ww + (r - 1)) * Cc + cih * 32 + slog * 8;
            bool valid = (fi < 4640) & (hh >= 0) & (hh < Hh) & (r >= 1) & (r <= Ww);
            if (!valid) src = zpage;
            gload16(src, As + (it * 512 + wbase) * 16);
          }
        }
        // stage B: 9 gload16/wave; u = hl*9+tap9
        {
#pragma unroll
          for (int it = 0; it < 9; ++it) {
            int fi = it * 512 + tid;
            int u = fi >> 8, c = fi & 255;
            int co = c >> 2, slot = c & 3;
            int slog = slot ^ ((co >> 1) & 3);
            int hl = (u >= 9), tap9 = u - 9 * hl;
            const u16* src = (hl ? w1l : w1h)
                + (kd * 9 + tap9) * 4096 + co * 64 + cih * 32 + slog * 8;
            gload16(src, Bs + (it * 512 + wbase) * 16);
          }
        }
        asm volatile("s_waitcnt vmcnt(0)" ::: "memory");
        __builtin_amdgcn_s_barrier();
        __builtin_amdgcn_sched_barrier(0);
        // compute: 9 taps x 48 MFMA per wave
        const char* Ab0 = As + (size_t)wid * 2 * SLICE_B;
#pragma unroll
        for (int kh = 0; kh < 3; ++kh) {
          const char* Ab = Ab0 + (size_t)kh * 2 * SLICE_B;
#pragma unroll
          for (int kw = 0; kw < 3; ++kw) {
            const int tap9 = kh * 3 + kw;
            bf16x8 ah[4], al[4], bh[4], bl[4];
#pragma unroll
            for (int m = 0; m < 4; ++m) {
              int row = r15 + 16 * m + kw;
              ah[m] = *frag_ptr(Ab, row, g);
              al[m] = *frag_ptr(Ab + SLICE_B, row, g);
            }
#pragma unroll
            for (int nt = 0; nt < 4; ++nt) {
              int co = r15 + 16 * nt;
              bh[nt] = *frag_ptr(Bs + tap9 * 4096, co, g);
              bl[nt] = *frag_ptr(Bs + (9 + tap9) * 4096, co, g);
            }
#pragma unroll
            for (int m = 0; m < 4; ++m)
#pragma unroll
              for (int nt = 0; nt < 4; ++nt) {
                acc[m][nt] = __builtin_amdgcn_mfma_f32_16x16x32_bf16(ah[m], bh[nt], acc[m][nt], 0, 0, 0);
                acc[m][nt] = __builtin_amdgcn_mfma_f32_16x16x32_bf16(al[m], bh[nt], acc[m][nt], 0, 0, 0);
                acc[m][nt] = __builtin_amdgcn_mfma_f32_16x16x32_bf16(ah[m], bl[nt], acc[m][nt], 0, 0, 0);
              }
          }
        }
      }
    }
    // epilogue: bias, BFP quant, relu, store bf16 (exact)
    const int h = h0 + wid;
    const size_t rowbase = ((size_t)(n * Tt + t) * Hh + h) * ((size_t)Ww * Cc);
#pragma unroll
    for (int nt = 0; nt < 4; ++nt) {
      int co = 16 * nt + r15;
      float e = e1[co];
      float sc = exp2f(7.0f - e), inv = exp2f(e - 7.0f);
      float bias = b1[co];
#pragma unroll
      for (int m = 0; m < 4; ++m)
#pragma unroll
        for (int j = 0; j < 4; ++j) {
          int w = 16 * m + 4 * g + j;
          if (w < Ww) {
            float v = acc[m][nt][j] + bias;
            float q = rintf(v * sc);
            q = fminf(fmaxf(q, -127.f), 127.f);
            v = fmaxf(q * inv, 0.0f);
            res1[rowbase + (size_t)w * Cc + co] = f32_to_bf16(v);
          }
        }
    }
}

// conv2: single-pass (a.w2h), 80KB LDS -> 2 blocks/CU
__global__ __launch_bounds__(512, 2) void conv2_mfma_kernel(
    const u16* __restrict__ a, const u16* __restrict__ w2h,
    const float* __restrict__ b2, const float* __restrict__ e2,
    const float* __restrict__ x, const u16* __restrict__ zpage,
    float* __restrict__ out)
{
    __shared__ __align__(16) char smem[C2_SMEM];
    char* As = smem;
    char* Bs = smem + C2_BOFF;

    const int tid = threadIdx.x;
    const int l = tid & 63, wid = tid >> 6;
    const int g = l >> 4, r15 = l & 15;
    const int wbase = tid & ~63;
    const int bid = (blockIdx.x & 7) * 112 + (blockIdx.x >> 3);
    const int hb = bid % 7;
    const int t  = (bid / 7) % Tt;
    const int n  = bid / (7 * Tt);
    const int h0 = hb * 8;

    f32x4 acc[4][4] = {};

#pragma unroll 1
    for (int cih = 0; cih < 2; ++cih) {
#pragma unroll 1
      for (int kd = 0; kd < 3; ++kd) {
        const int td = t + kd - 1;
        if (td < 0 || td >= Tt) continue;
        __builtin_amdgcn_sched_barrier(0);
        __builtin_amdgcn_s_barrier();
        __builtin_amdgcn_sched_barrier(0);
        // stage A: 5 gload16/wave (2320 valid chunks, tail -> pad)
        {
          const size_t tdbase = (size_t)(n * Tt + td) * ((size_t)Hh * Ww * Cc);
#pragma unroll
          for (int it = 0; it < 5; ++it) {
            int fi = it * 512 + tid;
            int u = fi / 232, c = fi - u * 232;
            int r = c >> 2, slot = c & 3;
            int hh = h0 - 1 + u;
            int slog = slot ^ ((r >> 1) & 3);
            const u16* src = a + tdbase
                + ((size_t)hh * Ww + (r - 1)) * Cc + cih * 32 + slog * 8;
            bool valid = (fi < 2320) & (hh >= 0) & (hh < Hh) & (r >= 1) & (r <= Ww);
            if (!valid) src = zpage;
            gload16(src, As + (it * 512 + wbase) * 16);
          }
        }
        // stage B: 5 gload16/wave (2304 valid chunks, tail -> pad)
        {
#pragma unroll
          for (int it = 0; it < 5; ++it) {
            int fi = it * 512 + tid;
            int u = fi >> 8, c = fi & 255;
            int co = c >> 2, slot = c & 3;
            int slog = slot ^ ((co >> 1) & 3);
            const u16* src = w2h + (kd * 9 + u) * 4096 + co * 64 + cih * 32 + slog * 8;
            if (fi >= 2304) src = zpage;
            gload16(src, Bs + (it * 512 + wbase) * 16);
          }
        }
        asm volatile("s_waitcnt vmcnt(0)" ::: "memory");
        __builtin_amdgcn_s_barrier();
        __builtin_amdgcn_sched_barrier(0);
        const char* Ab0 = As + (size_t)wid * SLICE_B;
#pragma unroll
        for (int kh = 0; kh < 3; ++kh) {
          const char* Ab = Ab0 + (size_t)kh * SLICE_B;
#pragma unroll
          for (int kw = 0; kw < 3; ++kw) {
            const int tap9 = kh * 3 + kw;
            bf16x8 af[4], bh[4];
#pragma unroll
            for (int m = 0; m < 4; ++m) {
              int row = r15 + 16 * m + kw;
              af[m] = *frag_ptr(Ab, row, g);
            }
#pragma unroll
            for (int nt = 0; nt < 4; ++nt) {
              int co = r15 + 16 * nt;
              bh[nt] = *frag_ptr(Bs + tap9 * 4096, co, g);
            }
#pragma unroll
            for (int m = 0; m < 4; ++m)
#pragma unroll
              for (int nt = 0; nt < 4; ++nt)
                acc[m][nt] = __builtin_amdgcn_mfma_f32_16x16x32_bf16(af[m], bh[nt], acc[m][nt], 0, 0, 0);
          }
        }
      }
    }
    // epilogue: conv-quant + identity-quant + relu -> f32 out (NCDHW)
    const int h = h0 + wid;
#pragma unroll
    for (int nt = 0; nt < 4; ++nt) {
      int co = 16 * nt + r15;
      float e = e2[co];
      float sc = exp2f(7.0f - e), inv = exp2f(e - 7.0f);
      float bias = b2[co];
#pragma unroll
      for (int m = 0; m < 4; ++m)
#pragma unroll
        for (int j = 0; j < 4; ++j) {
          int w = 16 * m + 4 * g + j;
          if (w < Ww) {
            float v = acc[m][nt][j] + bias;
            float q = rintf(v * sc);
            q = fminf(fmaxf(q, -127.f), 127.f);
            v = q * inv;
            size_t xi = (((size_t)(n * Cc + co) * Tt + t) * Hh + h) * Ww + w;
            float xv = x[xi];
            float qx = rintf(xv * sc);
            qx = fminf(fmaxf(qx, -127.f), 127.f);
            out[xi] = fmaxf(qx * inv + v, 0.0f);
          }
        }
    }
}

extern "C" void kernel_launch(void* const* d_in, const int* in_sizes, int n_in,
                              void* d_out, int out_size, void* d_ws, size_t ws_size,
                              hipStream_t stream) {
    const float* x  = (const float*)d_in[0];
    const float* w1 = (const float*)d_in[1];
    const float* b1 = (const float*)d_in[2];
    const float* w2 = (const float*)d_in[3];
    const float* b2 = (const float*)d_in[4];
    const float* e1 = (const float*)d_in[5];
    const float* e2 = (const float*)d_in[6];

    const size_t NE = 25690112;            // out elems = 8*64*16*56*56
    u16* xh = (u16*)d_out;                 // d_out doubles as xh/xl scratch
    u16* xl = xh + NE;
    char* ws = (char*)d_ws;
    u16* w1h = (u16*)(ws);
    u16* w1l = (u16*)(ws + 221184);
    u16* w2h = (u16*)(ws + 442368);
    u16* w2l = (u16*)(ws + 663552);
    u16* zpage = (u16*)(ws + 884736);      // 4KB zeros
    u16* res1  = (u16*)(ws + 888832);      // 51.4 MB

    prep_w_kernel<<<865, 256, 0, stream>>>(w1, w2, w1h, w1l, w2h, w2l, zpage);
    split_x_kernel<<<Nn * Tt * Hh, 256, 0, stream>>>(x, xh, xl);
    const int nwg = Nn * Tt * 7;           // 896
    conv1_mfma_kernel<<<nwg, 512, 0, stream>>>(xh, xl, w1h, w1l, b1, e1, zpage, res1);
    conv2_mfma_kernel<<<nwg, 512, 0, stream>>>(res1, w2h, b2, e2, x, zpage, (float*)d_out);
}